// Round 1
// baseline (882.672 us; speedup 1.0000x reference)
//
#include <hip/hip_runtime.h>
#include <math.h>

#define N_NODES 32768
#define N_EDGES 262144
#define EPS_C 0.24253562503633297f   // 1/sqrt(17)
#define NT 8                          // nodes per wave in node kernel

// ---------------------------------------------------------------------------
// Edge precompute: r, bessel radial basis w/ envelope, unit vectors Y1
// ---------------------------------------------------------------------------
__global__ __launch_bounds__(256) void edge_pre_kernel(
    const float* __restrict__ vectors, float* __restrict__ rbf, float* __restrict__ Y1)
{
    int e = blockIdx.x * 256 + threadIdx.x;
    float x = vectors[e * 3 + 0], y = vectors[e * 3 + 1], z = vectors[e * 3 + 2];
    float r2 = x * x + y * y + z * z + 1e-12f;
    float r = sqrtf(r2);
    float inv = 1.0f / r;
    Y1[e * 3 + 0] = x * inv;
    Y1[e * 3 + 1] = y * inv;
    Y1[e * 3 + 2] = z * inv;
    float rc = fmaxf(r, 1e-6f);
    float r6 = r2 * r2 * r2;
    float r7 = r6 * r;
    float r8 = r6 * r2;
    float env = (r < 1.0f) ? (1.0f - 28.0f * r6 + 48.0f * r7 - 21.0f * r8) : 0.0f;
    float sc = 1.41421356237309515f * env / rc;
#pragma unroll
    for (int j = 0; j < 8; ++j) {
        rbf[e * 8 + j] = sc * sinf((float)(j + 1) * 3.14159265358979323846f * rc);
    }
}

// ---------------------------------------------------------------------------
// Node init: s = embed_s[species], v = 0
// ---------------------------------------------------------------------------
__global__ __launch_bounds__(256) void init_kernel(
    const float* __restrict__ embed_s, const int* __restrict__ species,
    float* __restrict__ s, float* __restrict__ v)
{
    int idx = blockIdx.x * 256 + threadIdx.x;  // over N*64
    int n = idx >> 6, f = idx & 63;
    s[idx] = embed_s[species[n] * 64 + f];
    v[((size_t)n * 3 + 0) * 64 + f] = 0.0f;
    v[((size_t)n * 3 + 1) * 64 + f] = 0.0f;
    v[((size_t)n * 3 + 2) * 64 + f] = 0.0f;
}

// ---------------------------------------------------------------------------
// Edge kernel: one wave (64 lanes = channels) per edge; atomic scatter to agg
// ---------------------------------------------------------------------------
__global__ __launch_bounds__(256) void edge_kernel(
    const float* __restrict__ rbf, const float* __restrict__ Y1,
    const int* __restrict__ senders, const int* __restrict__ receivers,
    const float* __restrict__ s, const float* __restrict__ v,
    const float* __restrict__ Wr_i,       // [8, 320]
    float* __restrict__ agg_s, float* __restrict__ agg_v,
    int vzero)
{
    __shared__ float shW[2560];
    for (int idx = threadIdx.x; idx < 2560; idx += 256) shW[idx] = Wr_i[idx];
    __syncthreads();

    const int wid = threadIdx.x >> 6;
    const int f = threadIdx.x & 63;
    int group = blockIdx.x * 4 + wid;     // grid 4096 blocks -> 16384 groups, 16 edges each

    for (int e = group; e < N_EDGES; e += 16384) {
        int snd = senders[e];
        int rcv = receivers[e];
        float y0 = Y1[e * 3 + 0], y1 = Y1[e * 3 + 1], y2 = Y1[e * 3 + 2];
        // radial MLP weights: w[p] = sum_j rbf[j] * Wr[j, p*64+f]
        float w0 = 0.f, w1 = 0.f, w2 = 0.f, w3 = 0.f, w4 = 0.f;
#pragma unroll
        for (int j = 0; j < 8; ++j) {
            float rb = rbf[e * 8 + j];
            const float* Wj = shW + j * 320;
            w0 = fmaf(rb, Wj[f], w0);
            w1 = fmaf(rb, Wj[64 + f], w1);
            w2 = fmaf(rb, Wj[128 + f], w2);
            w3 = fmaf(rb, Wj[192 + f], w3);
            w4 = fmaf(rb, Wj[256 + f], w4);
        }
        float ss = s[(size_t)snd * 64 + f];
        float m0, m10, m11, m12;
        if (vzero) {
            m0 = w0 * ss;
            float ws2 = w2 * ss;
            m10 = ws2 * y0; m11 = ws2 * y1; m12 = ws2 * y2;
        } else {
            float vs0 = v[((size_t)snd * 3 + 0) * 64 + f];
            float vs1 = v[((size_t)snd * 3 + 1) * 64 + f];
            float vs2 = v[((size_t)snd * 3 + 2) * 64 + f];
            float dot = vs0 * y0 + vs1 * y1 + vs2 * y2;
            m0 = w0 * ss + w1 * dot;
            float c0 = vs1 * y2 - vs2 * y1;
            float c1 = vs2 * y0 - vs0 * y2;
            float c2 = vs0 * y1 - vs1 * y0;
            float ws2 = w2 * ss;
            m10 = ws2 * y0 + w3 * vs0 + w4 * c0;
            m11 = ws2 * y1 + w3 * vs1 + w4 * c1;
            m12 = ws2 * y2 + w3 * vs2 + w4 * c2;
        }
        unsafeAtomicAdd(&agg_s[(size_t)rcv * 64 + f], m0);
        unsafeAtomicAdd(&agg_v[((size_t)rcv * 3 + 0) * 64 + f], m10);
        unsafeAtomicAdd(&agg_v[((size_t)rcv * 3 + 1) * 64 + f], m11);
        unsafeAtomicAdd(&agg_v[((size_t)rcv * 3 + 2) * 64 + f], m12);
    }
}

// ---------------------------------------------------------------------------
// Node kernel helpers: out[f] = sum_g x[g] * W[g*64+f], 8 nodes at a time.
// x broadcast from LDS (float4), W column loaded once per g, reused 8x.
// ---------------------------------------------------------------------------
__device__ __forceinline__ void dot8(const float* __restrict__ W, const float* shx,
                                     int f, float* acc)
{
#pragma unroll 4
    for (int g = 0; g < 64; g += 4) {
        float w0 = W[(g + 0) * 64 + f];
        float w1 = W[(g + 1) * 64 + f];
        float w2 = W[(g + 2) * 64 + f];
        float w3 = W[(g + 3) * 64 + f];
#pragma unroll
        for (int t = 0; t < NT; ++t) {
            float4 x = *(const float4*)(shx + t * 64 + g);
            acc[t] = fmaf(x.x, w0, acc[t]);
            acc[t] = fmaf(x.y, w1, acc[t]);
            acc[t] = fmaf(x.z, w2, acc[t]);
            acc[t] = fmaf(x.w, w3, acc[t]);
        }
    }
}

__device__ __forceinline__ float dot1(const float* __restrict__ W, const float* shx, int f)
{
    float a = 0.f;
#pragma unroll 4
    for (int g = 0; g < 64; g += 4) {
        float4 x = *(const float4*)(shx + g);
        a = fmaf(x.x, W[(g + 0) * 64 + f], a);
        a = fmaf(x.y, W[(g + 1) * 64 + f], a);
        a = fmaf(x.z, W[(g + 2) * 64 + f], a);
        a = fmaf(x.w, W[(g + 3) * 64 + f], a);
    }
    return a;
}

// ---------------------------------------------------------------------------
// Node kernel: block = 4 waves, each wave handles NT=8 nodes, lane = channel.
// ---------------------------------------------------------------------------
__global__ __launch_bounds__(256) void node_kernel(
    const float* __restrict__ agg_s, const float* __restrict__ agg_v,
    float* __restrict__ s, float* __restrict__ v,
    const float* __restrict__ Wls, const float* __restrict__ Wlv,
    const float* __restrict__ skip_s, const float* __restrict__ skip_v,
    const float* __restrict__ pw_i, const float* __restrict__ Wps,
    const float* __restrict__ Wpv,
    const float* __restrict__ Wread0, const float* __restrict__ Wr1a,
    const float* __restrict__ Wr1b,
    const int* __restrict__ species, float* __restrict__ out,
    int has_skip, int mode, int slot)
{
    const int wid = threadIdx.x >> 6;
    const int f = threadIdx.x & 63;
    const int base = (blockIdx.x * 4 + wid) * NT;
    __shared__ __align__(16) float sh_all[4][NT * 64];
    float* sh = sh_all[wid];

    int spec[NT];
#pragma unroll
    for (int t = 0; t < NT; ++t) spec[t] = species[base + t];

    // ---- s2 = (agg_s * EPS) @ Wls
#pragma unroll
    for (int t = 0; t < NT; ++t) sh[t * 64 + f] = agg_s[(size_t)(base + t) * 64 + f] * EPS_C;
    __syncthreads();
    float s2[NT];
#pragma unroll
    for (int t = 0; t < NT; ++t) s2[t] = 0.f;
    dot8(Wls, sh, f, s2);

    // ---- v2[k] = (agg_v[:, :, k] * EPS) @ Wlv
    float v2[3][NT];
    for (int k = 0; k < 3; ++k) {
        __syncthreads();
#pragma unroll
        for (int t = 0; t < NT; ++t)
            sh[t * 64 + f] = agg_v[((size_t)(base + t) * 3 + k) * 64 + f] * EPS_C;
        __syncthreads();
#pragma unroll
        for (int t = 0; t < NT; ++t) v2[k][t] = 0.f;
        dot8(Wlv, sh, f, v2[k]);
    }

    // ---- per-species skip connection on PRE-interaction s, v
    float sc_s[NT], sc_v[3][NT];
    if (has_skip) {
        __syncthreads();
#pragma unroll
        for (int t = 0; t < NT; ++t) sh[t * 64 + f] = s[(size_t)(base + t) * 64 + f];
        __syncthreads();
#pragma unroll
        for (int t = 0; t < NT; ++t) sc_s[t] = dot1(skip_s + spec[t] * 4096, sh + t * 64, f);
        for (int k = 0; k < 3; ++k) {
            __syncthreads();
#pragma unroll
            for (int t = 0; t < NT; ++t)
                sh[t * 64 + f] = v[((size_t)(base + t) * 3 + k) * 64 + f];
            __syncthreads();
#pragma unroll
            for (int t = 0; t < NT; ++t)
                sc_v[k][t] = dot1(skip_v + spec[t] * 4096, sh + t * 64, f);
        }
    }

    // ---- symmetric product basis (elementwise in channel)
    float ps[NT], pvs[NT];
#pragma unroll
    for (int t = 0; t < NT; ++t) {
        const float* p = pw_i + spec[t] * 576 + f;
        float p0 = p[0], p1 = p[64], p2 = p[128], p3 = p[192], p4 = p[256];
        float p5 = p[320], p6 = p[384], p7 = p[448], p8 = p[512];
        float x = s2[t];
        float vv = v2[0][t] * v2[0][t] + v2[1][t] * v2[1][t] + v2[2][t] * v2[2][t];
        float x2 = x * x;
        ps[t] = p0 * x + p1 * x2 + p2 * vv + p3 * x2 * x + p4 * x * vv;
        pvs[t] = p5 + p6 * x + p7 * x2 + p8 * vv;
    }

    // ---- s_new = ps @ Wps (+ skip), write back
    __syncthreads();
#pragma unroll
    for (int t = 0; t < NT; ++t) sh[t * 64 + f] = ps[t];
    __syncthreads();
    float s_new[NT];
#pragma unroll
    for (int t = 0; t < NT; ++t) s_new[t] = 0.f;
    dot8(Wps, sh, f, s_new);
#pragma unroll
    for (int t = 0; t < NT; ++t) {
        if (has_skip) s_new[t] += sc_s[t];
        s[(size_t)(base + t) * 64 + f] = s_new[t];
    }

    // ---- v_new[k] = pv[k] @ Wpv (+ skip), write back
    for (int k = 0; k < 3; ++k) {
        __syncthreads();
#pragma unroll
        for (int t = 0; t < NT; ++t) sh[t * 64 + f] = pvs[t] * v2[k][t];
        __syncthreads();
        float acc[NT];
#pragma unroll
        for (int t = 0; t < NT; ++t) acc[t] = 0.f;
        dot8(Wpv, sh, f, acc);
#pragma unroll
        for (int t = 0; t < NT; ++t) {
            float val = acc[t] + (has_skip ? sc_v[k][t] : 0.f);
            v[((size_t)(base + t) * 3 + k) * 64 + f] = val;
        }
    }

    // ---- readout
    if (mode == 0) {
        float w0 = Wread0[f];
#pragma unroll
        for (int t = 0; t < NT; ++t) {
            float a = s_new[t] * w0;
            for (int off = 32; off; off >>= 1) a += __shfl_down(a, off);
            if (f == 0) out[(size_t)(base + t) * 2 + slot] = a;
        }
    } else {
        __syncthreads();
#pragma unroll
        for (int t = 0; t < NT; ++t) sh[t * 64 + f] = s_new[t];
        __syncthreads();
        // 8 nodes x 16 hidden = 128 (t,h) pairs over 64 lanes (2 per lane)
        int hh = f & 15;
        int t0 = f >> 4;
        int t1 = 4 + (f >> 4);
        float a0 = 0.f, a1 = 0.f;
        for (int g = 0; g < 64; ++g) {
            float wa = Wr1a[g * 16 + hh];
            a0 = fmaf(sh[t0 * 64 + g], wa, a0);
            a1 = fmaf(sh[t1 * 64 + g], wa, a1);
        }
        float wb = Wr1b[hh];
        float r0 = (a0 / (1.f + expf(-a0))) * wb;
        float r1 = (a1 / (1.f + expf(-a1))) * wb;
        for (int off = 8; off; off >>= 1) {
            r0 += __shfl_down(r0, off);
            r1 += __shfl_down(r1, off);
        }
        if ((f & 15) == 0) {
            out[(size_t)(base + t0) * 2 + slot] = r0;
            out[(size_t)(base + t1) * 2 + slot] = r1;
        }
    }
}

// ---------------------------------------------------------------------------
extern "C" void kernel_launch(void* const* d_in, const int* in_sizes, int n_in,
                              void* d_out, int out_size, void* d_ws, size_t ws_size,
                              hipStream_t stream)
{
    const float* vectors = (const float*)d_in[0];
    const float* embed_s = (const float*)d_in[1];
    const float* Wr      = (const float*)d_in[2];   // [2,8,320]
    const float* Wls     = (const float*)d_in[3];   // [2,64,64]
    const float* Wlv     = (const float*)d_in[4];
    const float* skip_s  = (const float*)d_in[5];   // [10,64,64]
    const float* skip_v  = (const float*)d_in[6];
    const float* pw      = (const float*)d_in[7];   // [2,10,9,64]
    const float* Wps     = (const float*)d_in[8];
    const float* Wpv     = (const float*)d_in[9];
    const float* Wread0  = (const float*)d_in[10];  // [64,1]
    const float* Wr1a    = (const float*)d_in[11];  // [64,16]
    const float* Wr1b    = (const float*)d_in[12];  // [16,1]
    const int* senders   = (const int*)d_in[13];
    const int* receivers = (const int*)d_in[14];
    const int* species   = (const int*)d_in[15];
    float* out = (float*)d_out;

    // workspace layout (floats)
    float* ws = (float*)d_ws;
    float* rbf   = ws; ws += (size_t)N_EDGES * 8;   // 8 MB
    float* Y1    = ws; ws += (size_t)N_EDGES * 3;   // 3 MB
    float* s     = ws; ws += (size_t)N_NODES * 64;  // 8 MB
    float* v     = ws; ws += (size_t)N_NODES * 192; // 24 MB  [N,3,64]
    float* agg_s = ws; ws += (size_t)N_NODES * 64;  // 8 MB   (contiguous with agg_v)
    float* agg_v = ws; ws += (size_t)N_NODES * 192; // 24 MB

    edge_pre_kernel<<<N_EDGES / 256, 256, 0, stream>>>(vectors, rbf, Y1);
    init_kernel<<<N_NODES * 64 / 256, 256, 0, stream>>>(embed_s, species, s, v);

    for (int i = 0; i < 2; ++i) {
        hipMemsetAsync(agg_s, 0, (size_t)N_NODES * 256 * sizeof(float), stream);
        edge_kernel<<<4096, 256, 0, stream>>>(
            rbf, Y1, senders, receivers, s, v, Wr + i * 2560, agg_s, agg_v,
            (i == 0) ? 1 : 0);
        node_kernel<<<N_NODES / (4 * NT), 256, 0, stream>>>(
            agg_s, agg_v, s, v,
            Wls + i * 4096, Wlv + i * 4096, skip_s, skip_v,
            pw + i * 5760, Wps + i * 4096, Wpv + i * 4096,
            Wread0, Wr1a, Wr1b, species, out,
            (i > 0) ? 1 : 0, (i == 1) ? 1 : 0, i);
    }
}

// Round 2
// 801.503 us; speedup vs baseline: 1.1013x; 1.1013x over previous
//
#include <hip/hip_runtime.h>
#include <math.h>

#define N_NODES 32768
#define N_EDGES 262144
#define EPS_C 0.24253562503633297f   // 1/sqrt(17)
#define NT 8                          // nodes per wave in node kernel

// ---------------------------------------------------------------------------
// Edge precompute: r, bessel radial basis w/ envelope, unit vectors Y1 [E,4]
// ---------------------------------------------------------------------------
__global__ __launch_bounds__(256) void edge_pre_kernel(
    const float* __restrict__ vectors, float* __restrict__ rbf, float* __restrict__ Y1)
{
    int e = blockIdx.x * 256 + threadIdx.x;
    float x = vectors[e * 3 + 0], y = vectors[e * 3 + 1], z = vectors[e * 3 + 2];
    float r2 = x * x + y * y + z * z + 1e-12f;
    float r = sqrtf(r2);
    float inv = 1.0f / r;
    float4 yv = make_float4(x * inv, y * inv, z * inv, 0.0f);
    *(float4*)(Y1 + e * 4) = yv;
    float rc = fmaxf(r, 1e-6f);
    float r6 = r2 * r2 * r2;
    float r7 = r6 * r;
    float r8 = r6 * r2;
    float env = (r < 1.0f) ? (1.0f - 28.0f * r6 + 48.0f * r7 - 21.0f * r8) : 0.0f;
    float sc = 1.41421356237309515f * env / rc;
#pragma unroll
    for (int j = 0; j < 8; ++j) {
        rbf[e * 8 + j] = sc * sinf((float)(j + 1) * 3.14159265358979323846f * rc);
    }
}

// ---------------------------------------------------------------------------
// Node init: s = embed_s[species], v = 0
// ---------------------------------------------------------------------------
__global__ __launch_bounds__(256) void init_kernel(
    const float* __restrict__ embed_s, const int* __restrict__ species,
    float* __restrict__ s, float* __restrict__ v)
{
    int idx = blockIdx.x * 256 + threadIdx.x;  // over N*64
    int n = idx >> 6, f = idx & 63;
    s[idx] = embed_s[species[n] * 64 + f];
    v[((size_t)n * 3 + 0) * 64 + f] = 0.0f;
    v[((size_t)n * 3 + 1) * 64 + f] = 0.0f;
    v[((size_t)n * 3 + 2) * 64 + f] = 0.0f;
}

// ---------------------------------------------------------------------------
// Edge kernel: one wave (64 lanes = channels) per edge; atomic scatter to agg.
// Two edges per loop iteration for doubled ILP on the gather chain.
// ---------------------------------------------------------------------------
__global__ __launch_bounds__(256) void edge_kernel(
    const float* __restrict__ rbf, const float* __restrict__ Y1,
    const int* __restrict__ senders, const int* __restrict__ receivers,
    const float* __restrict__ s, const float* __restrict__ v,
    const float* __restrict__ Wr_i,       // [8, 320]
    float* __restrict__ agg_s, float* __restrict__ agg_v,
    int vzero)
{
    __shared__ float shW[2560];
    for (int idx = threadIdx.x; idx < 2560; idx += 256) shW[idx] = Wr_i[idx];
    __syncthreads();

    const int wid = threadIdx.x >> 6;
    const int f = threadIdx.x & 63;
    int group = blockIdx.x * 4 + wid;     // 16384 groups; 8 iterations x 2 edges

    for (int e0 = group; e0 < N_EDGES / 2; e0 += 16384) {
        int eA = e0, eB = e0 + N_EDGES / 2;
        int sndA = senders[eA], rcvA = receivers[eA];
        int sndB = senders[eB], rcvB = receivers[eB];
        float4 yA = *(const float4*)(Y1 + (size_t)eA * 4);
        float4 yB = *(const float4*)(Y1 + (size_t)eB * 4);
        float4 rA0 = *(const float4*)(rbf + (size_t)eA * 8);
        float4 rA1 = *(const float4*)(rbf + (size_t)eA * 8 + 4);
        float4 rB0 = *(const float4*)(rbf + (size_t)eB * 8);
        float4 rB1 = *(const float4*)(rbf + (size_t)eB * 8 + 4);
        float ssA = s[(size_t)sndA * 64 + f];
        float ssB = s[(size_t)sndB * 64 + f];

        float wA0 = 0.f, wA1 = 0.f, wA2 = 0.f, wA3 = 0.f, wA4 = 0.f;
        float wB0 = 0.f, wB1 = 0.f, wB2 = 0.f, wB3 = 0.f, wB4 = 0.f;
        float rbA[8] = {rA0.x, rA0.y, rA0.z, rA0.w, rA1.x, rA1.y, rA1.z, rA1.w};
        float rbB[8] = {rB0.x, rB0.y, rB0.z, rB0.w, rB1.x, rB1.y, rB1.z, rB1.w};
#pragma unroll
        for (int j = 0; j < 8; ++j) {
            const float* Wj = shW + j * 320;
            float c0 = Wj[f], c1 = Wj[64 + f], c2 = Wj[128 + f];
            float c3 = Wj[192 + f], c4 = Wj[256 + f];
            wA0 = fmaf(rbA[j], c0, wA0);  wB0 = fmaf(rbB[j], c0, wB0);
            wA1 = fmaf(rbA[j], c1, wA1);  wB1 = fmaf(rbB[j], c1, wB1);
            wA2 = fmaf(rbA[j], c2, wA2);  wB2 = fmaf(rbB[j], c2, wB2);
            wA3 = fmaf(rbA[j], c3, wA3);  wB3 = fmaf(rbB[j], c3, wB3);
            wA4 = fmaf(rbA[j], c4, wA4);  wB4 = fmaf(rbB[j], c4, wB4);
        }

        float m0A, m10A, m11A, m12A, m0B, m10B, m11B, m12B;
        if (vzero) {
            m0A = wA0 * ssA;
            float wsA = wA2 * ssA;
            m10A = wsA * yA.x; m11A = wsA * yA.y; m12A = wsA * yA.z;
            m0B = wB0 * ssB;
            float wsB = wB2 * ssB;
            m10B = wsB * yB.x; m11B = wsB * yB.y; m12B = wsB * yB.z;
        } else {
            float vA0 = v[((size_t)sndA * 3 + 0) * 64 + f];
            float vA1 = v[((size_t)sndA * 3 + 1) * 64 + f];
            float vA2 = v[((size_t)sndA * 3 + 2) * 64 + f];
            float vB0 = v[((size_t)sndB * 3 + 0) * 64 + f];
            float vB1 = v[((size_t)sndB * 3 + 1) * 64 + f];
            float vB2 = v[((size_t)sndB * 3 + 2) * 64 + f];
            float dotA = vA0 * yA.x + vA1 * yA.y + vA2 * yA.z;
            float dotB = vB0 * yB.x + vB1 * yB.y + vB2 * yB.z;
            m0A = wA0 * ssA + wA1 * dotA;
            m0B = wB0 * ssB + wB1 * dotB;
            float cA0 = vA1 * yA.z - vA2 * yA.y;
            float cA1 = vA2 * yA.x - vA0 * yA.z;
            float cA2 = vA0 * yA.y - vA1 * yA.x;
            float cB0 = vB1 * yB.z - vB2 * yB.y;
            float cB1 = vB2 * yB.x - vB0 * yB.z;
            float cB2 = vB0 * yB.y - vB1 * yB.x;
            float wsA = wA2 * ssA, wsB = wB2 * ssB;
            m10A = wsA * yA.x + wA3 * vA0 + wA4 * cA0;
            m11A = wsA * yA.y + wA3 * vA1 + wA4 * cA1;
            m12A = wsA * yA.z + wA3 * vA2 + wA4 * cA2;
            m10B = wsB * yB.x + wB3 * vB0 + wB4 * cB0;
            m11B = wsB * yB.y + wB3 * vB1 + wB4 * cB1;
            m12B = wsB * yB.z + wB3 * vB2 + wB4 * cB2;
        }
        unsafeAtomicAdd(&agg_s[(size_t)rcvA * 64 + f], m0A);
        unsafeAtomicAdd(&agg_v[((size_t)rcvA * 3 + 0) * 64 + f], m10A);
        unsafeAtomicAdd(&agg_v[((size_t)rcvA * 3 + 1) * 64 + f], m11A);
        unsafeAtomicAdd(&agg_v[((size_t)rcvA * 3 + 2) * 64 + f], m12A);
        unsafeAtomicAdd(&agg_s[(size_t)rcvB * 64 + f], m0B);
        unsafeAtomicAdd(&agg_v[((size_t)rcvB * 3 + 0) * 64 + f], m10B);
        unsafeAtomicAdd(&agg_v[((size_t)rcvB * 3 + 1) * 64 + f], m11B);
        unsafeAtomicAdd(&agg_v[((size_t)rcvB * 3 + 2) * 64 + f], m12B);
    }
}

// ---------------------------------------------------------------------------
// out[f] = sum_g x[g] * W[g*64+f], 8 nodes at a time; W staged in LDS.
// Weight reads: lane f -> bank f%32, 2-way aliasing (free). x reads: uniform
// address b128 broadcast (free).
// ---------------------------------------------------------------------------
__device__ __forceinline__ void dot8s(const float* __restrict__ shW,
                                      const float* __restrict__ shx,
                                      int f, float* acc)
{
#pragma unroll 4
    for (int g = 0; g < 64; g += 4) {
        float w0 = shW[(g + 0) * 64 + f];
        float w1 = shW[(g + 1) * 64 + f];
        float w2 = shW[(g + 2) * 64 + f];
        float w3 = shW[(g + 3) * 64 + f];
#pragma unroll
        for (int t = 0; t < NT; ++t) {
            float4 x = *(const float4*)(shx + t * 64 + g);
            acc[t] = fmaf(x.x, w0, acc[t]);
            acc[t] = fmaf(x.y, w1, acc[t]);
            acc[t] = fmaf(x.z, w2, acc[t]);
            acc[t] = fmaf(x.w, w3, acc[t]);
        }
    }
}

// Per-node weight matrices (per-species skip): 8 independent load->fma chains
__device__ __forceinline__ void dot8g(const float* const* __restrict__ Wt,
                                      const float* __restrict__ shx,
                                      int f, float* acc)
{
#pragma unroll 2
    for (int g = 0; g < 64; g += 4) {
        float4 x[NT];
#pragma unroll
        for (int t = 0; t < NT; ++t) x[t] = *(const float4*)(shx + t * 64 + g);
#pragma unroll
        for (int t = 0; t < NT; ++t) {
            const float* W = Wt[t] + g * 64 + f;
            acc[t] = fmaf(x[t].x, W[0],   acc[t]);
            acc[t] = fmaf(x[t].y, W[64],  acc[t]);
            acc[t] = fmaf(x[t].z, W[128], acc[t]);
            acc[t] = fmaf(x[t].w, W[192], acc[t]);
        }
    }
}

// ---------------------------------------------------------------------------
// Node kernel: block = 4 waves, each wave handles NT=8 nodes, lane = channel.
// Shared weight matrix of the current phase staged in LDS (16KB).
// ---------------------------------------------------------------------------
__global__ __launch_bounds__(256, 4) void node_kernel(
    const float* __restrict__ agg_s, const float* __restrict__ agg_v,
    float* __restrict__ s, float* __restrict__ v,
    const float* __restrict__ Wls, const float* __restrict__ Wlv,
    const float* __restrict__ skip_s, const float* __restrict__ skip_v,
    const float* __restrict__ pw_i, const float* __restrict__ Wps,
    const float* __restrict__ Wpv,
    const float* __restrict__ Wread0, const float* __restrict__ Wr1a,
    const float* __restrict__ Wr1b,
    const int* __restrict__ species, float* __restrict__ out,
    int has_skip, int mode, int slot)
{
    const int wid = threadIdx.x >> 6;
    const int f = threadIdx.x & 63;
    const int base = (blockIdx.x * 4 + wid) * NT;
    __shared__ __align__(16) float shWm[4096];        // current 64x64 weight
    __shared__ __align__(16) float sh_all[4][NT * 64];
    float* sh = sh_all[wid];

#define STAGE_W(src) do { \
        __syncthreads(); \
        for (int idx = threadIdx.x; idx < 1024; idx += 256) \
            ((float4*)shWm)[idx] = ((const float4*)(src))[idx]; \
        __syncthreads(); } while (0)

    int spec[NT];
#pragma unroll
    for (int t = 0; t < NT; ++t) spec[t] = species[base + t];

    // ---- s2 = (agg_s * EPS) @ Wls
    STAGE_W(Wls);
#pragma unroll
    for (int t = 0; t < NT; ++t) sh[t * 64 + f] = agg_s[(size_t)(base + t) * 64 + f] * EPS_C;
    __syncthreads();
    float s2[NT];
#pragma unroll
    for (int t = 0; t < NT; ++t) s2[t] = 0.f;
    dot8s(shWm, sh, f, s2);

    // ---- v2[k] = (agg_v[:, k, :] * EPS) @ Wlv
    float v2[3][NT];
    STAGE_W(Wlv);
    for (int k = 0; k < 3; ++k) {
        __syncthreads();
#pragma unroll
        for (int t = 0; t < NT; ++t)
            sh[t * 64 + f] = agg_v[((size_t)(base + t) * 3 + k) * 64 + f] * EPS_C;
        __syncthreads();
#pragma unroll
        for (int t = 0; t < NT; ++t) v2[k][t] = 0.f;
        dot8s(shWm, sh, f, v2[k]);
    }

    // ---- per-species skip connection on PRE-interaction s, v (global weights)
    float sc_s[NT], sc_v[3][NT];
    if (has_skip) {
        const float* Wt[NT];
#pragma unroll
        for (int t = 0; t < NT; ++t) Wt[t] = skip_s + spec[t] * 4096;
        __syncthreads();
#pragma unroll
        for (int t = 0; t < NT; ++t) sh[t * 64 + f] = s[(size_t)(base + t) * 64 + f];
        __syncthreads();
#pragma unroll
        for (int t = 0; t < NT; ++t) sc_s[t] = 0.f;
        dot8g(Wt, sh, f, sc_s);
#pragma unroll
        for (int t = 0; t < NT; ++t) Wt[t] = skip_v + spec[t] * 4096;
        for (int k = 0; k < 3; ++k) {
            __syncthreads();
#pragma unroll
            for (int t = 0; t < NT; ++t)
                sh[t * 64 + f] = v[((size_t)(base + t) * 3 + k) * 64 + f];
            __syncthreads();
#pragma unroll
            for (int t = 0; t < NT; ++t) sc_v[k][t] = 0.f;
            dot8g(Wt, sh, f, sc_v[k]);
        }
    }

    // ---- symmetric product basis (elementwise in channel)
    float ps[NT], pvs[NT];
#pragma unroll
    for (int t = 0; t < NT; ++t) {
        const float* p = pw_i + spec[t] * 576 + f;
        float p0 = p[0], p1 = p[64], p2 = p[128], p3 = p[192], p4 = p[256];
        float p5 = p[320], p6 = p[384], p7 = p[448], p8 = p[512];
        float x = s2[t];
        float vv = v2[0][t] * v2[0][t] + v2[1][t] * v2[1][t] + v2[2][t] * v2[2][t];
        float x2 = x * x;
        ps[t] = p0 * x + p1 * x2 + p2 * vv + p3 * x2 * x + p4 * x * vv;
        pvs[t] = p5 + p6 * x + p7 * x2 + p8 * vv;
    }

    // ---- s_new = ps @ Wps (+ skip), write back
    STAGE_W(Wps);
#pragma unroll
    for (int t = 0; t < NT; ++t) sh[t * 64 + f] = ps[t];
    __syncthreads();
    float s_new[NT];
#pragma unroll
    for (int t = 0; t < NT; ++t) s_new[t] = 0.f;
    dot8s(shWm, sh, f, s_new);
#pragma unroll
    for (int t = 0; t < NT; ++t) {
        if (has_skip) s_new[t] += sc_s[t];
        s[(size_t)(base + t) * 64 + f] = s_new[t];
    }

    // ---- v_new[k] = pv[k] @ Wpv (+ skip), write back
    STAGE_W(Wpv);
    for (int k = 0; k < 3; ++k) {
        __syncthreads();
#pragma unroll
        for (int t = 0; t < NT; ++t) sh[t * 64 + f] = pvs[t] * v2[k][t];
        __syncthreads();
        float acc[NT];
#pragma unroll
        for (int t = 0; t < NT; ++t) acc[t] = 0.f;
        dot8s(shWm, sh, f, acc);
#pragma unroll
        for (int t = 0; t < NT; ++t) {
            float val = acc[t] + (has_skip ? sc_v[k][t] : 0.f);
            v[((size_t)(base + t) * 3 + k) * 64 + f] = val;
        }
    }

    // ---- readout
    if (mode == 0) {
        float w0 = Wread0[f];
#pragma unroll
        for (int t = 0; t < NT; ++t) {
            float a = s_new[t] * w0;
            for (int off = 32; off; off >>= 1) a += __shfl_down(a, off);
            if (f == 0) out[(size_t)(base + t) * 2 + slot] = a;
        }
    } else {
        __syncthreads();
#pragma unroll
        for (int t = 0; t < NT; ++t) sh[t * 64 + f] = s_new[t];
        __syncthreads();
        // 8 nodes x 16 hidden = 128 (t,h) pairs over 64 lanes (2 per lane)
        int hh = f & 15;
        int t0 = f >> 4;
        int t1 = 4 + (f >> 4);
        float a0 = 0.f, a1 = 0.f;
        for (int g = 0; g < 64; ++g) {
            float wa = Wr1a[g * 16 + hh];
            a0 = fmaf(sh[t0 * 64 + g], wa, a0);
            a1 = fmaf(sh[t1 * 64 + g], wa, a1);
        }
        float wb = Wr1b[hh];
        float r0 = (a0 / (1.f + expf(-a0))) * wb;
        float r1 = (a1 / (1.f + expf(-a1))) * wb;
        for (int off = 8; off; off >>= 1) {
            r0 += __shfl_down(r0, off);
            r1 += __shfl_down(r1, off);
        }
        if ((f & 15) == 0) {
            out[(size_t)(base + t0) * 2 + slot] = r0;
            out[(size_t)(base + t1) * 2 + slot] = r1;
        }
    }
#undef STAGE_W
}

// ---------------------------------------------------------------------------
extern "C" void kernel_launch(void* const* d_in, const int* in_sizes, int n_in,
                              void* d_out, int out_size, void* d_ws, size_t ws_size,
                              hipStream_t stream)
{
    const float* vectors = (const float*)d_in[0];
    const float* embed_s = (const float*)d_in[1];
    const float* Wr      = (const float*)d_in[2];   // [2,8,320]
    const float* Wls     = (const float*)d_in[3];   // [2,64,64]
    const float* Wlv     = (const float*)d_in[4];
    const float* skip_s  = (const float*)d_in[5];   // [10,64,64]
    const float* skip_v  = (const float*)d_in[6];
    const float* pw      = (const float*)d_in[7];   // [2,10,9,64]
    const float* Wps     = (const float*)d_in[8];
    const float* Wpv     = (const float*)d_in[9];
    const float* Wread0  = (const float*)d_in[10];  // [64,1]
    const float* Wr1a    = (const float*)d_in[11];  // [64,16]
    const float* Wr1b    = (const float*)d_in[12];  // [16,1]
    const int* senders   = (const int*)d_in[13];
    const int* receivers = (const int*)d_in[14];
    const int* species   = (const int*)d_in[15];
    float* out = (float*)d_out;

    // workspace layout (floats)
    float* ws = (float*)d_ws;
    float* rbf   = ws; ws += (size_t)N_EDGES * 8;   // 8 MB
    float* Y1    = ws; ws += (size_t)N_EDGES * 4;   // 4 MB (padded)
    float* s     = ws; ws += (size_t)N_NODES * 64;  // 8 MB
    float* v     = ws; ws += (size_t)N_NODES * 192; // 24 MB  [N,3,64]
    float* agg_s = ws; ws += (size_t)N_NODES * 64;  // 8 MB   (contiguous with agg_v)
    float* agg_v = ws; ws += (size_t)N_NODES * 192; // 24 MB

    edge_pre_kernel<<<N_EDGES / 256, 256, 0, stream>>>(vectors, rbf, Y1);
    init_kernel<<<N_NODES * 64 / 256, 256, 0, stream>>>(embed_s, species, s, v);

    for (int i = 0; i < 2; ++i) {
        hipMemsetAsync(agg_s, 0, (size_t)N_NODES * 256 * sizeof(float), stream);
        edge_kernel<<<4096, 256, 0, stream>>>(
            rbf, Y1, senders, receivers, s, v, Wr + i * 2560, agg_s, agg_v,
            (i == 0) ? 1 : 0);
        node_kernel<<<N_NODES / (4 * NT), 256, 0, stream>>>(
            agg_s, agg_v, s, v,
            Wls + i * 4096, Wlv + i * 4096, skip_s, skip_v,
            pw + i * 5760, Wps + i * 4096, Wpv + i * 4096,
            Wread0, Wr1a, Wr1b, species, out,
            (i > 0) ? 1 : 0, (i == 1) ? 1 : 0, i);
    }
}

// Round 3
// 578.097 us; speedup vs baseline: 1.5269x; 1.3865x over previous
//
#include <hip/hip_runtime.h>
#include <math.h>

#define N_NODES 32768
#define N_EDGES 262144
#define EPS_C 0.24253562503633297f   // 1/sqrt(17)
#define NT 8                          // nodes per wave in node kernel

// ---------------------------------------------------------------------------
// Edge precompute: r, bessel radial basis w/ envelope, unit vectors Y1 [E,4]
// ---------------------------------------------------------------------------
__global__ __launch_bounds__(256) void edge_pre_kernel(
    const float* __restrict__ vectors, float* __restrict__ rbf, float* __restrict__ Y1)
{
    int e = blockIdx.x * 256 + threadIdx.x;
    float x = vectors[e * 3 + 0], y = vectors[e * 3 + 1], z = vectors[e * 3 + 2];
    float r2 = x * x + y * y + z * z + 1e-12f;
    float r = sqrtf(r2);
    float inv = 1.0f / r;
    float4 yv = make_float4(x * inv, y * inv, z * inv, 0.0f);
    *(float4*)(Y1 + e * 4) = yv;
    float rc = fmaxf(r, 1e-6f);
    float r6 = r2 * r2 * r2;
    float r7 = r6 * r;
    float r8 = r6 * r2;
    float env = (r < 1.0f) ? (1.0f - 28.0f * r6 + 48.0f * r7 - 21.0f * r8) : 0.0f;
    float sc = 1.41421356237309515f * env / rc;
#pragma unroll
    for (int j = 0; j < 8; ++j) {
        rbf[e * 8 + j] = sc * sinf((float)(j + 1) * 3.14159265358979323846f * rc);
    }
}

// ---------------------------------------------------------------------------
// Node init: s = embed_s[species], v = 0
// ---------------------------------------------------------------------------
__global__ __launch_bounds__(256) void init_kernel(
    const float* __restrict__ embed_s, const int* __restrict__ species,
    float* __restrict__ s, float* __restrict__ v)
{
    int idx = blockIdx.x * 256 + threadIdx.x;  // over N*64
    int n = idx >> 6, f = idx & 63;
    s[idx] = embed_s[species[n] * 64 + f];
    v[((size_t)n * 3 + 0) * 64 + f] = 0.0f;
    v[((size_t)n * 3 + 1) * 64 + f] = 0.0f;
    v[((size_t)n * 3 + 2) * 64 + f] = 0.0f;
}

// ---------------------------------------------------------------------------
// CSR build: histogram -> single-block scan -> scatter
// ---------------------------------------------------------------------------
__global__ __launch_bounds__(256) void hist_kernel(
    const int* __restrict__ receivers, int* __restrict__ counts)
{
    int e = blockIdx.x * 256 + threadIdx.x;
    atomicAdd(&counts[receivers[e]], 1);
}

__global__ __launch_bounds__(1024) void scan_kernel(
    const int* __restrict__ counts, int* __restrict__ row_start, int* __restrict__ cursor)
{
    // 32768 nodes = 1024 threads x 32
    __shared__ int wave_tot[16];
    int tid = threadIdx.x;
    int c[32];
    int sum = 0;
#pragma unroll
    for (int i = 0; i < 32; ++i) { c[i] = counts[tid * 32 + i]; sum += c[i]; }
    int lane = tid & 63, wv = tid >> 6;
    int x = sum;
#pragma unroll
    for (int off = 1; off < 64; off <<= 1) {
        int y = __shfl_up(x, off);
        if (lane >= off) x += y;
    }
    if (lane == 63) wave_tot[wv] = x;
    __syncthreads();
    if (wv == 0 && lane < 16) {
        int t = wave_tot[lane];
#pragma unroll
        for (int off = 1; off < 16; off <<= 1) {
            int y = __shfl_up(t, off);
            if (lane >= off) t += y;
        }
        wave_tot[lane] = t;
    }
    __syncthreads();
    int excl = x - sum + (wv ? wave_tot[wv - 1] : 0);
    int run = excl;
#pragma unroll
    for (int i = 0; i < 32; ++i) {
        row_start[tid * 32 + i] = run;
        cursor[tid * 32 + i] = run;
        run += c[i];
    }
    if (tid == 1023) row_start[32768] = run;
}

__global__ __launch_bounds__(256) void scatter_kernel(
    const int* __restrict__ receivers, int* __restrict__ cursor, int* __restrict__ edge_ids)
{
    int e = blockIdx.x * 256 + threadIdx.x;
    int slot = atomicAdd(&cursor[receivers[e]], 1);
    edge_ids[slot] = e;
}

// ---------------------------------------------------------------------------
// Gather edge kernel: wave (64 lanes = channels) owns 8 receiver nodes;
// iterates CSR edge lists, accumulates agg in registers, single plain store.
// No atomics, no memset. Random access only on read side (s/v: L3-resident).
// ---------------------------------------------------------------------------
__global__ __launch_bounds__(256) void gather_kernel(
    const float* __restrict__ rbf, const float* __restrict__ Y1,
    const int* __restrict__ senders, const int* __restrict__ edge_ids,
    const int* __restrict__ row_start,
    const float* __restrict__ s, const float* __restrict__ v,
    const float* __restrict__ Wr_i,       // [8, 320]
    float* __restrict__ agg_s, float* __restrict__ agg_v,
    int vzero)
{
    __shared__ float shW[2560];
    for (int idx = threadIdx.x; idx < 2560; idx += 256) shW[idx] = Wr_i[idx];
    __syncthreads();

    const int wid = threadIdx.x >> 6;
    const int f = threadIdx.x & 63;
    const int base = (blockIdx.x * 4 + wid) * 8;

    for (int t = 0; t < 8; ++t) {
        int n = base + t;
        int beg = row_start[n], end = row_start[n + 1];
        float a0 = 0.f, a1 = 0.f, a2 = 0.f, a3 = 0.f;
        // 1-ahead prefetch of the index chain
        int eid = (beg < end) ? edge_ids[beg] : 0;
        int snd = (beg < end) ? senders[eid] : 0;
        for (int p = beg; p < end; ++p) {
            int pn = p + 1;
            int eid_n = (pn < end) ? edge_ids[pn] : 0;
            float4 y = *(const float4*)(Y1 + (size_t)eid * 4);
            float4 r0 = *(const float4*)(rbf + (size_t)eid * 8);
            float4 r1 = *(const float4*)(rbf + (size_t)eid * 8 + 4);
            float ss = s[(size_t)snd * 64 + f];
            int snd_n = (pn < end) ? senders[eid_n] : 0;

            float rb[8] = {r0.x, r0.y, r0.z, r0.w, r1.x, r1.y, r1.z, r1.w};
            float w0 = 0.f, w1 = 0.f, w2 = 0.f, w3 = 0.f, w4 = 0.f;
#pragma unroll
            for (int j = 0; j < 8; ++j) {
                const float* Wj = shW + j * 320;
                w0 = fmaf(rb[j], Wj[f], w0);
                w1 = fmaf(rb[j], Wj[64 + f], w1);
                w2 = fmaf(rb[j], Wj[128 + f], w2);
                w3 = fmaf(rb[j], Wj[192 + f], w3);
                w4 = fmaf(rb[j], Wj[256 + f], w4);
            }
            if (vzero) {
                a0 += w0 * ss;
                float ws2 = w2 * ss;
                a1 += ws2 * y.x; a2 += ws2 * y.y; a3 += ws2 * y.z;
            } else {
                float vs0 = v[((size_t)snd * 3 + 0) * 64 + f];
                float vs1 = v[((size_t)snd * 3 + 1) * 64 + f];
                float vs2 = v[((size_t)snd * 3 + 2) * 64 + f];
                float dot = vs0 * y.x + vs1 * y.y + vs2 * y.z;
                a0 += w0 * ss + w1 * dot;
                float c0 = vs1 * y.z - vs2 * y.y;
                float c1 = vs2 * y.x - vs0 * y.z;
                float c2 = vs0 * y.y - vs1 * y.x;
                float ws2 = w2 * ss;
                a1 += ws2 * y.x + w3 * vs0 + w4 * c0;
                a2 += ws2 * y.y + w3 * vs1 + w4 * c1;
                a3 += ws2 * y.z + w3 * vs2 + w4 * c2;
            }
            eid = eid_n; snd = snd_n;
        }
        agg_s[(size_t)n * 64 + f] = a0;
        agg_v[((size_t)n * 3 + 0) * 64 + f] = a1;
        agg_v[((size_t)n * 3 + 1) * 64 + f] = a2;
        agg_v[((size_t)n * 3 + 2) * 64 + f] = a3;
    }
}

// ---------------------------------------------------------------------------
// out[f] = sum_g x[g] * W[g*64+f], 8 nodes at a time; W staged in LDS.
// ---------------------------------------------------------------------------
__device__ __forceinline__ void dot8s(const float* __restrict__ shW,
                                      const float* __restrict__ shx,
                                      int f, float* acc)
{
#pragma unroll 4
    for (int g = 0; g < 64; g += 4) {
        float w0 = shW[(g + 0) * 64 + f];
        float w1 = shW[(g + 1) * 64 + f];
        float w2 = shW[(g + 2) * 64 + f];
        float w3 = shW[(g + 3) * 64 + f];
#pragma unroll
        for (int t = 0; t < NT; ++t) {
            float4 x = *(const float4*)(shx + t * 64 + g);
            acc[t] = fmaf(x.x, w0, acc[t]);
            acc[t] = fmaf(x.y, w1, acc[t]);
            acc[t] = fmaf(x.z, w2, acc[t]);
            acc[t] = fmaf(x.w, w3, acc[t]);
        }
    }
}

// Per-node weight matrices (per-species skip): 8 independent load->fma chains
__device__ __forceinline__ void dot8g(const float* const* __restrict__ Wt,
                                      const float* __restrict__ shx,
                                      int f, float* acc)
{
#pragma unroll 2
    for (int g = 0; g < 64; g += 4) {
        float4 x[NT];
#pragma unroll
        for (int t = 0; t < NT; ++t) x[t] = *(const float4*)(shx + t * 64 + g);
#pragma unroll
        for (int t = 0; t < NT; ++t) {
            const float* W = Wt[t] + g * 64 + f;
            acc[t] = fmaf(x[t].x, W[0],   acc[t]);
            acc[t] = fmaf(x[t].y, W[64],  acc[t]);
            acc[t] = fmaf(x[t].z, W[128], acc[t]);
            acc[t] = fmaf(x[t].w, W[192], acc[t]);
        }
    }
}

// ---------------------------------------------------------------------------
// Node kernel: block = 4 waves, each wave handles NT=8 nodes, lane = channel.
// ---------------------------------------------------------------------------
__global__ __launch_bounds__(256, 4) void node_kernel(
    const float* __restrict__ agg_s, const float* __restrict__ agg_v,
    float* __restrict__ s, float* __restrict__ v,
    const float* __restrict__ Wls, const float* __restrict__ Wlv,
    const float* __restrict__ skip_s, const float* __restrict__ skip_v,
    const float* __restrict__ pw_i, const float* __restrict__ Wps,
    const float* __restrict__ Wpv,
    const float* __restrict__ Wread0, const float* __restrict__ Wr1a,
    const float* __restrict__ Wr1b,
    const int* __restrict__ species, float* __restrict__ out,
    int has_skip, int mode, int slot)
{
    const int wid = threadIdx.x >> 6;
    const int f = threadIdx.x & 63;
    const int base = (blockIdx.x * 4 + wid) * NT;
    __shared__ __align__(16) float shWm[4096];        // current 64x64 weight
    __shared__ __align__(16) float sh_all[4][NT * 64];
    float* sh = sh_all[wid];

#define STAGE_W(src) do { \
        __syncthreads(); \
        for (int idx = threadIdx.x; idx < 1024; idx += 256) \
            ((float4*)shWm)[idx] = ((const float4*)(src))[idx]; \
        __syncthreads(); } while (0)

    int spec[NT];
#pragma unroll
    for (int t = 0; t < NT; ++t) spec[t] = species[base + t];

    // ---- s2 = (agg_s * EPS) @ Wls
    STAGE_W(Wls);
#pragma unroll
    for (int t = 0; t < NT; ++t) sh[t * 64 + f] = agg_s[(size_t)(base + t) * 64 + f] * EPS_C;
    __syncthreads();
    float s2[NT];
#pragma unroll
    for (int t = 0; t < NT; ++t) s2[t] = 0.f;
    dot8s(shWm, sh, f, s2);

    // ---- v2[k] = (agg_v[:, k, :] * EPS) @ Wlv
    float v2[3][NT];
    STAGE_W(Wlv);
    for (int k = 0; k < 3; ++k) {
        __syncthreads();
#pragma unroll
        for (int t = 0; t < NT; ++t)
            sh[t * 64 + f] = agg_v[((size_t)(base + t) * 3 + k) * 64 + f] * EPS_C;
        __syncthreads();
#pragma unroll
        for (int t = 0; t < NT; ++t) v2[k][t] = 0.f;
        dot8s(shWm, sh, f, v2[k]);
    }

    // ---- per-species skip connection on PRE-interaction s, v (global weights)
    float sc_s[NT], sc_v[3][NT];
    if (has_skip) {
        const float* Wt[NT];
#pragma unroll
        for (int t = 0; t < NT; ++t) Wt[t] = skip_s + spec[t] * 4096;
        __syncthreads();
#pragma unroll
        for (int t = 0; t < NT; ++t) sh[t * 64 + f] = s[(size_t)(base + t) * 64 + f];
        __syncthreads();
#pragma unroll
        for (int t = 0; t < NT; ++t) sc_s[t] = 0.f;
        dot8g(Wt, sh, f, sc_s);
#pragma unroll
        for (int t = 0; t < NT; ++t) Wt[t] = skip_v + spec[t] * 4096;
        for (int k = 0; k < 3; ++k) {
            __syncthreads();
#pragma unroll
            for (int t = 0; t < NT; ++t)
                sh[t * 64 + f] = v[((size_t)(base + t) * 3 + k) * 64 + f];
            __syncthreads();
#pragma unroll
            for (int t = 0; t < NT; ++t) sc_v[k][t] = 0.f;
            dot8g(Wt, sh, f, sc_v[k]);
        }
    }

    // ---- symmetric product basis (elementwise in channel)
    float ps[NT], pvs[NT];
#pragma unroll
    for (int t = 0; t < NT; ++t) {
        const float* p = pw_i + spec[t] * 576 + f;
        float p0 = p[0], p1 = p[64], p2 = p[128], p3 = p[192], p4 = p[256];
        float p5 = p[320], p6 = p[384], p7 = p[448], p8 = p[512];
        float x = s2[t];
        float vv = v2[0][t] * v2[0][t] + v2[1][t] * v2[1][t] + v2[2][t] * v2[2][t];
        float x2 = x * x;
        ps[t] = p0 * x + p1 * x2 + p2 * vv + p3 * x2 * x + p4 * x * vv;
        pvs[t] = p5 + p6 * x + p7 * x2 + p8 * vv;
    }

    // ---- s_new = ps @ Wps (+ skip), write back
    STAGE_W(Wps);
#pragma unroll
    for (int t = 0; t < NT; ++t) sh[t * 64 + f] = ps[t];
    __syncthreads();
    float s_new[NT];
#pragma unroll
    for (int t = 0; t < NT; ++t) s_new[t] = 0.f;
    dot8s(shWm, sh, f, s_new);
#pragma unroll
    for (int t = 0; t < NT; ++t) {
        if (has_skip) s_new[t] += sc_s[t];
        s[(size_t)(base + t) * 64 + f] = s_new[t];
    }

    // ---- v_new[k] = pv[k] @ Wpv (+ skip), write back
    STAGE_W(Wpv);
    for (int k = 0; k < 3; ++k) {
        __syncthreads();
#pragma unroll
        for (int t = 0; t < NT; ++t) sh[t * 64 + f] = pvs[t] * v2[k][t];
        __syncthreads();
        float acc[NT];
#pragma unroll
        for (int t = 0; t < NT; ++t) acc[t] = 0.f;
        dot8s(shWm, sh, f, acc);
#pragma unroll
        for (int t = 0; t < NT; ++t) {
            float val = acc[t] + (has_skip ? sc_v[k][t] : 0.f);
            v[((size_t)(base + t) * 3 + k) * 64 + f] = val;
        }
    }

    // ---- readout
    if (mode == 0) {
        float w0 = Wread0[f];
#pragma unroll
        for (int t = 0; t < NT; ++t) {
            float a = s_new[t] * w0;
            for (int off = 32; off; off >>= 1) a += __shfl_down(a, off);
            if (f == 0) out[(size_t)(base + t) * 2 + slot] = a;
        }
    } else {
        __syncthreads();
#pragma unroll
        for (int t = 0; t < NT; ++t) sh[t * 64 + f] = s_new[t];
        __syncthreads();
        // 8 nodes x 16 hidden = 128 (t,h) pairs over 64 lanes (2 per lane)
        int hh = f & 15;
        int t0 = f >> 4;
        int t1 = 4 + (f >> 4);
        float a0 = 0.f, a1 = 0.f;
        for (int g = 0; g < 64; ++g) {
            float wa = Wr1a[g * 16 + hh];
            a0 = fmaf(sh[t0 * 64 + g], wa, a0);
            a1 = fmaf(sh[t1 * 64 + g], wa, a1);
        }
        float wb = Wr1b[hh];
        float r0 = (a0 / (1.f + expf(-a0))) * wb;
        float r1 = (a1 / (1.f + expf(-a1))) * wb;
        for (int off = 8; off; off >>= 1) {
            r0 += __shfl_down(r0, off);
            r1 += __shfl_down(r1, off);
        }
        if ((f & 15) == 0) {
            out[(size_t)(base + t0) * 2 + slot] = r0;
            out[(size_t)(base + t1) * 2 + slot] = r1;
        }
    }
#undef STAGE_W
}

// ---------------------------------------------------------------------------
extern "C" void kernel_launch(void* const* d_in, const int* in_sizes, int n_in,
                              void* d_out, int out_size, void* d_ws, size_t ws_size,
                              hipStream_t stream)
{
    const float* vectors = (const float*)d_in[0];
    const float* embed_s = (const float*)d_in[1];
    const float* Wr      = (const float*)d_in[2];   // [2,8,320]
    const float* Wls     = (const float*)d_in[3];   // [2,64,64]
    const float* Wlv     = (const float*)d_in[4];
    const float* skip_s  = (const float*)d_in[5];   // [10,64,64]
    const float* skip_v  = (const float*)d_in[6];
    const float* pw      = (const float*)d_in[7];   // [2,10,9,64]
    const float* Wps     = (const float*)d_in[8];
    const float* Wpv     = (const float*)d_in[9];
    const float* Wread0  = (const float*)d_in[10];  // [64,1]
    const float* Wr1a    = (const float*)d_in[11];  // [64,16]
    const float* Wr1b    = (const float*)d_in[12];  // [16,1]
    const int* senders   = (const int*)d_in[13];
    const int* receivers = (const int*)d_in[14];
    const int* species   = (const int*)d_in[15];
    float* out = (float*)d_out;

    // workspace layout (floats / ints)
    float* ws = (float*)d_ws;
    float* rbf   = ws; ws += (size_t)N_EDGES * 8;   // 8 MB
    float* Y1    = ws; ws += (size_t)N_EDGES * 4;   // 4 MB (padded)
    float* s     = ws; ws += (size_t)N_NODES * 64;  // 8 MB
    float* v     = ws; ws += (size_t)N_NODES * 192; // 24 MB  [N,3,64]
    float* agg_s = ws; ws += (size_t)N_NODES * 64;  // 8 MB
    float* agg_v = ws; ws += (size_t)N_NODES * 192; // 24 MB
    int* counts    = (int*)ws; ws += N_NODES;       // 128 KB
    int* row_start = (int*)ws; ws += N_NODES + 4;
    int* cursor    = (int*)ws; ws += N_NODES;
    int* edge_ids  = (int*)ws; ws += N_EDGES;       // 1 MB

    edge_pre_kernel<<<N_EDGES / 256, 256, 0, stream>>>(vectors, rbf, Y1);
    init_kernel<<<N_NODES * 64 / 256, 256, 0, stream>>>(embed_s, species, s, v);

    // CSR build (once; reused by both interactions)
    hipMemsetAsync(counts, 0, N_NODES * sizeof(int), stream);
    hist_kernel<<<N_EDGES / 256, 256, 0, stream>>>(receivers, counts);
    scan_kernel<<<1, 1024, 0, stream>>>(counts, row_start, cursor);
    scatter_kernel<<<N_EDGES / 256, 256, 0, stream>>>(receivers, cursor, edge_ids);

    for (int i = 0; i < 2; ++i) {
        gather_kernel<<<N_NODES / 32, 256, 0, stream>>>(
            rbf, Y1, senders, edge_ids, row_start, s, v, Wr + i * 2560,
            agg_s, agg_v, (i == 0) ? 1 : 0);
        node_kernel<<<N_NODES / (4 * NT), 256, 0, stream>>>(
            agg_s, agg_v, s, v,
            Wls + i * 4096, Wlv + i * 4096, skip_s, skip_v,
            pw + i * 5760, Wps + i * 4096, Wpv + i * 4096,
            Wread0, Wr1a, Wr1b, species, out,
            (i > 0) ? 1 : 0, (i == 1) ? 1 : 0, i);
    }
}